// Round 2
// baseline (807.687 us; speedup 1.0000x reference)
//
#include <hip/hip_runtime.h>
#include <hip/hip_bf16.h>
#include <math.h>

#define NN 100000
#define NE 1600000
#define NB_SCAN ((NN + 255) / 256)  // 391
#define NBUK 98                     // dst >> 10, 99999>>10 = 97
#define CHUNK 2048                  // edges per bucket_scatter block

typedef __attribute__((ext_vector_type(8))) short bf8_t;   // 8 bf16 = 4 VGPRs
typedef __attribute__((ext_vector_type(4))) float f4_t;    // 4 fp32 acc
typedef __attribute__((ext_vector_type(8))) unsigned short us8_t;  // 16B

__device__ __forceinline__ ushort f2b(float f) {
  __hip_bfloat16 h = __float2bfloat16(f);  // RNE
  return *(ushort*)&h;
}
__device__ __forceinline__ float b2f(ushort u) {
  return __uint_as_float(((unsigned)u) << 16);
}

// ---------------------------------------------------------------------------
// bf16 MFMA GEMM: Y[M,N] = X[M,K] @ W[K,N] (bf16 out, fp32 W staged in-kernel)
// ---------------------------------------------------------------------------
template <int K, int N, bool XF32>
__global__ __launch_bounds__(256) void mfma_gemm(
    const void* __restrict__ Xv, const float* __restrict__ Wf,
    ushort* __restrict__ Y, int M) {
  __shared__ ushort xs[64][72];
  __shared__ ushort wsh[64][72];

  const int tid = threadIdx.x;
  const int wave = tid >> 6;
  const int lane = tid & 63;
  const int row0 = blockIdx.x * 64;

  f4_t acc[4];
#pragma unroll
  for (int t = 0; t < 4; t++) acc[t] = (f4_t){0.f, 0.f, 0.f, 0.f};

  for (int k0 = 0; k0 < K; k0 += 64) {
#pragma unroll
    for (int i = 0; i < 4; i++) {
      int fidx = i * 256 + tid;
      int row = fidx >> 4;
      int kq = (fidx & 15) * 4;
      ushort4 uv = make_ushort4(0, 0, 0, 0);
      if (row0 + row < M) {
        if (XF32) {
          const float* Xf = (const float*)Xv;
          float4 xv = *(const float4*)&Xf[(long)(row0 + row) * K + k0 + kq];
          uv = make_ushort4(f2b(xv.x), f2b(xv.y), f2b(xv.z), f2b(xv.w));
        } else {
          const ushort* Xb = (const ushort*)Xv;
          uv = *(const ushort4*)&Xb[(long)(row0 + row) * K + k0 + kq];
        }
      }
      *(ushort4*)&xs[row][kq] = uv;
    }
#pragma unroll
    for (int i = 0; i < 4; i++) {
      int widx = i * 256 + tid;
      int n = widx & 63;
      int kq = (widx >> 6) * 4;
      ushort4 uv = make_ushort4(0, 0, 0, 0);
      if (n < N) {
        uv.x = f2b(Wf[(long)(k0 + kq + 0) * N + n]);
        uv.y = f2b(Wf[(long)(k0 + kq + 1) * N + n]);
        uv.z = f2b(Wf[(long)(k0 + kq + 2) * N + n]);
        uv.w = f2b(Wf[(long)(k0 + kq + 3) * N + n]);
      }
      *(ushort4*)&wsh[n][kq] = uv;
    }
    __syncthreads();
#pragma unroll
    for (int s = 0; s < 2; s++) {
      bf8_t af = *(const bf8_t*)&xs[wave * 16 + (lane & 15)][s * 32 + (lane >> 4) * 8];
#pragma unroll
      for (int t = 0; t < 4; t++) {
        bf8_t bf = *(const bf8_t*)&wsh[t * 16 + (lane & 15)][s * 32 + (lane >> 4) * 8];
        acc[t] = __builtin_amdgcn_mfma_f32_16x16x32_bf16(af, bf, acc[t], 0, 0, 0);
      }
    }
    __syncthreads();
  }
  const int crow0 = row0 + wave * 16 + (lane >> 4) * 4;
  const int ccol = lane & 15;
#pragma unroll
  for (int t = 0; t < 4; t++) {
    int col = ccol + t * 16;
    if (col < N) {
#pragma unroll
      for (int r = 0; r < 4; r++) {
        int row = crow0 + r;
        if (row < M) Y[(long)row * N + col] = f2b(acc[t][r]);
      }
    }
  }
}

// ---------------------------------------------------------------------------
// CSR build: histogram -> scan -> bucket scatter -> fine fill
// ---------------------------------------------------------------------------
__global__ __launch_bounds__(256) void hist_kernel(const int* __restrict__ dst,
                                                   int* __restrict__ deg) {
  int idx = blockIdx.x * 256 + threadIdx.x;
  if (idx < NE / 4) {
    int4 d4 = ((const int4*)dst)[idx];
    atomicAdd(&deg[d4.x], 1);
    atomicAdd(&deg[d4.y], 1);
    atomicAdd(&deg[d4.z], 1);
    atomicAdd(&deg[d4.w], 1);
  }
}

__global__ __launch_bounds__(256) void scan_blocks_kernel(
    const int* __restrict__ deg, int* __restrict__ rowptr,
    int* __restrict__ partials, int n) {
  __shared__ int tmp[256];
  int tid = threadIdx.x;
  int gid = blockIdx.x * 256 + tid;
  int v = (gid < n) ? deg[gid] : 0;
  tmp[tid] = v;
  __syncthreads();
#pragma unroll
  for (int off = 1; off < 256; off <<= 1) {
    int t = (tid >= off) ? tmp[tid - off] : 0;
    __syncthreads();
    tmp[tid] += t;
    __syncthreads();
  }
  if (gid < n) rowptr[gid] = tmp[tid] - v;
  if (tid == 255) partials[blockIdx.x] = tmp[255];
}

// scan partials; then bcur[b] = scanned partials[4b] (== rowptr[b<<10],
// since (b<<10)%256==0 makes the local exclusive prefix zero there).
__global__ __launch_bounds__(64) void scan_partials_bcur_kernel(
    int* __restrict__ p, int n, int* __restrict__ bcur) {
  int lane = threadIdx.x;
  int carry = 0;
  for (int base = 0; base < n; base += 64) {
    int i = base + lane;
    int v = (i < n) ? p[i] : 0;
#pragma unroll
    for (int off = 1; off < 64; off <<= 1) {
      int t = __shfl_up(v, off, 64);
      if (lane >= off) v += t;
    }
    int total = __shfl(v, 63, 64);
    int ex = __shfl_up(v, 1, 64);
    if (lane == 0) ex = 0;
    if (i < n) p[i] = carry + ex;
    carry += total;
  }
  __syncthreads();
  for (int b = lane; b < NBUK; b += 64) bcur[b] = p[4 * b];
}

__global__ __launch_bounds__(256) void add_offsets_kernel(
    int* __restrict__ rowptr, int* __restrict__ cursor,
    const int* __restrict__ partials, int n) {
  int gid = blockIdx.x * 256 + threadIdx.x;
  if (gid < n) {
    int v = rowptr[gid] + partials[blockIdx.x];
    rowptr[gid] = v;
    cursor[gid] = v;
  }
}

// Pass B: group edges by bucket (dst>>10) with block-aggregated reservation.
// Writes are contiguous runs per (block,bucket) -> ~1x write amplification.
__global__ __launch_bounds__(256) void bucket_scatter_kernel(
    const int* __restrict__ src, const int* __restrict__ dst,
    const float* __restrict__ ew, int* __restrict__ bcur,
    int2* __restrict__ esw, int* __restrict__ ed, int n) {
  __shared__ int lcnt[NBUK];
  __shared__ int lbase[NBUK];
  const int tid = threadIdx.x;
  const int e0 = blockIdx.x * CHUNK;
  for (int i = tid; i < NBUK; i += 256) lcnt[i] = 0;
  __syncthreads();

  int es[8], ds[8], rk[8];
  float wv[8];
#pragma unroll
  for (int k = 0; k < 8; k++) {
    int e = e0 + k * 256 + tid;
    if (e < n) {
      es[k] = src[e];
      ds[k] = dst[e];
      wv[k] = ew[e];
      rk[k] = atomicAdd(&lcnt[ds[k] >> 10], 1);
    } else {
      ds[k] = -1;
    }
  }
  __syncthreads();
  for (int i = tid; i < NBUK; i += 256)
    lbase[i] = lcnt[i] ? atomicAdd(&bcur[i], lcnt[i]) : 0;
  __syncthreads();
#pragma unroll
  for (int k = 0; k < 8; k++) {
    if (ds[k] >= 0) {
      int p = lbase[ds[k] >> 10] + rk[k];
      esw[p] = make_int2(es[k], __float_as_int(wv[k]));
      ed[p] = ds[k];
    }
  }
}

// Pass C: edges now bucket-grouped; per-node scatter stays inside one
// bucket's <=132KB CSR window -> L2-absorbed writes.
__global__ __launch_bounds__(256) void fine_fill_kernel(
    const int2* __restrict__ esw, const int* __restrict__ ed,
    int* __restrict__ cursor, int2* __restrict__ csr, int n) {
  int i = blockIdx.x * 256 + threadIdx.x;
  if (i < n) {
    int d = ed[i];
    int pos = atomicAdd(&cursor[d], 1);
    csr[pos] = esw[i];
  }
}

// ---------------------------------------------------------------------------
// Fused aggregation + next-layer GEMM (D_in=64 -> NOUT):
//   row  = sum_{e in row} w_e * H[src_e]          (gather, D=64 bf16)
//   t    = relu(row + b_in)                       (fp32)
//   out  = bf16( t @ W )                          (per-row matvec, W in LDS)
// 8 rows per wave, 4 waves/block -> 32 rows/block; W staged fp32 once/block.
// ---------------------------------------------------------------------------
template <int NOUT>
__global__ __launch_bounds__(256) void agg_mm_kernel(
    const int* __restrict__ rowptr, const int* __restrict__ deg,
    const int2* __restrict__ csr, const ushort* __restrict__ H,
    const float* __restrict__ bin, const float* __restrict__ Wf,
    ushort* __restrict__ out, int nR) {
  __shared__ float Wsh[64 * NOUT];
  const int tid = threadIdx.x;
#pragma unroll
  for (int i = 0; i < (64 * NOUT + 255) / 256; i++) {
    int idx = i * 256 + tid;
    if (idx < 64 * NOUT) Wsh[idx] = Wf[idx];
  }
  const int lane = tid & 63;
  const int wave = tid >> 6;
  const int g = lane >> 3;
  const int sub = lane & 7;
  const int cn = (lane < NOUT) ? lane : 0;  // lanes>=NOUT read col0 (broadcast)
  float bk[8];
#pragma unroll
  for (int k = 0; k < 8; k++) bk[k] = bin[sub * 8 + k];
  __syncthreads();

  const int rbase = blockIdx.x * 32 + wave * 8;
  for (int i = 0; i < 8; i++) {
    const int r = rbase + i;
    if (r >= nR) return;
    const int beg = rowptr[r];
    const int d = deg[r];
    float acc[8];
#pragma unroll
    for (int k = 0; k < 8; k++) acc[k] = 0.f;
    for (int j0 = 0; j0 < d; j0 += 8) {
      int jj = j0 + g;
      int2 cw = (jj < d) ? csr[beg + jj] : make_int2(0, 0);  // w=0 pad
      float w = __int_as_float(cw.y);
      us8_t hv = *(const us8_t*)&H[(long)cw.x * 64 + sub * 8];
#pragma unroll
      for (int k = 0; k < 8; k++) acc[k] += w * b2f(hv[k]);
    }
#pragma unroll
    for (int off = 8; off < 64; off <<= 1)
#pragma unroll
      for (int k = 0; k < 8; k++) acc[k] += __shfl_xor(acc[k], off, 64);
    // all 64 lanes now hold the full row: lane(sub) has row[sub*8+k]
    float tv[8];
#pragma unroll
    for (int k = 0; k < 8; k++) tv[k] = fmaxf(acc[k] + bk[k], 0.f);
    float o = 0.f;
#pragma unroll
    for (int m = 0; m < 64; m++) {
      float rv = __shfl(tv[m & 7], m >> 3, 8);  // broadcast row[m] within 8-lane grp
      o = fmaf(rv, Wsh[m * NOUT + cn], o);
    }
    if (lane < NOUT) out[(long)r * NOUT + lane] = f2b(o);
  }
}

// ---------------------------------------------------------------------------
// Layer-3 fused: chunked aggregation (D=40) + bias + log_softmax, fp32 out.
// ---------------------------------------------------------------------------
__global__ __launch_bounds__(256) void agg_lsm_kernel(
    const int* __restrict__ rowptr, const int* __restrict__ deg,
    const int2* __restrict__ csr, const ushort* __restrict__ H,
    const float* __restrict__ b, float* __restrict__ out, int nR) {
  int lane = threadIdx.x & 63;
  int r = blockIdx.x * 4 + (threadIdx.x >> 6);
  if (r >= nR) return;
  int beg = rowptr[r];
  int d = deg[r];
  int g = lane >> 3;
  int sub = lane & 7;
  float acc[8];
#pragma unroll
  for (int k = 0; k < 8; k++) acc[k] = 0.f;

  for (int j0 = 0; j0 < d; j0 += 8) {
    int jj = j0 + g;
    int2 cw = (jj < d) ? csr[beg + jj] : make_int2(0, 0);
    float w = __int_as_float(cw.y);
    if (sub < 5) {
      us8_t hv = *(const us8_t*)&H[(long)cw.x * 40 + sub * 8];
#pragma unroll
      for (int k = 0; k < 8; k++) acc[k] += w * b2f(hv[k]);
    }
  }
#pragma unroll
  for (int off = 8; off < 64; off <<= 1)
#pragma unroll
    for (int k = 0; k < 8; k++) acc[k] += __shfl_xor(acc[k], off, 64);

  float v[8];
  float m = -INFINITY, s = 0.f;
  if (sub < 5) {
#pragma unroll
    for (int k = 0; k < 8; k++) {
      v[k] = acc[k] + b[sub * 8 + k];
      m = fmaxf(m, v[k]);
    }
  }
#pragma unroll
  for (int off = 1; off < 8; off <<= 1) m = fmaxf(m, __shfl_xor(m, off, 64));
  if (sub < 5) {
#pragma unroll
    for (int k = 0; k < 8; k++) s += __expf(v[k] - m);
  }
#pragma unroll
  for (int off = 1; off < 8; off <<= 1) s += __shfl_xor(s, off, 64);

  if (g == 0 && sub < 5) {
    float lg = m + __logf(s);
    float4 o0 = make_float4(v[0] - lg, v[1] - lg, v[2] - lg, v[3] - lg);
    float4 o1 = make_float4(v[4] - lg, v[5] - lg, v[6] - lg, v[7] - lg);
    *(float4*)&out[(long)r * 40 + sub * 8] = o0;
    *(float4*)&out[(long)r * 40 + sub * 8 + 4] = o1;
  }
}

extern "C" void kernel_launch(void* const* d_in, const int* in_sizes, int n_in,
                              void* d_out, int out_size, void* d_ws,
                              size_t ws_size, hipStream_t stream) {
  const int* edge_index = (const int*)d_in[0];
  const float* features = (const float*)d_in[1];
  const float* ew = (const float*)d_in[2];
  const float* W1 = (const float*)d_in[3];
  const float* b1 = (const float*)d_in[4];
  const float* W2 = (const float*)d_in[5];
  const float* b2 = (const float*)d_in[6];
  const float* W3 = (const float*)d_in[7];
  const float* b3 = (const float*)d_in[8];
  float* out = (float*)d_out;
  const int* src = edge_index;
  const int* dst = edge_index + NE;

  // workspace layout
  char* p = (char*)d_ws;
  int2* csr = (int2*)p;              p += (size_t)NE * 8;       // 12.8 MB
  int2* esw = (int2*)p;              p += (size_t)NE * 8;       // 12.8 MB
  int* ed = (int*)p;                 p += (size_t)NE * 4;       // 6.4 MB
  int* deg = (int*)p;                p += (size_t)NN * 4;
  int* rowptr = (int*)p;             p += (size_t)NN * 4;
  int* cursor = (int*)p;             p += (size_t)NN * 4;
  int* partials = (int*)p;           p += 1024 * 4;
  int* bcur = (int*)p;               p += 128 * 4;
  ushort* hb = (ushort*)p;           p += (size_t)NN * 64 * 2;  // layer buffers
  ushort* xb = (ushort*)p;           p += (size_t)NN * 64 * 2;

  dim3 blk(256);
  const int gemm_grid = (NN + 63) / 64;
  const int edge_grid = (NE + 255) / 256;
  const int hist_grid = (NE / 4 + 255) / 256;
  const int agg_grid = (NN + 31) / 32;
  const int row_grid = (NN + 3) / 4;

  // ---- CSR build (by dst) ----
  hipMemsetAsync(deg, 0, NN * sizeof(int), stream);
  hist_kernel<<<hist_grid, blk, 0, stream>>>(dst, deg);
  scan_blocks_kernel<<<NB_SCAN, blk, 0, stream>>>(deg, rowptr, partials, NN);
  scan_partials_bcur_kernel<<<1, 64, 0, stream>>>(partials, NB_SCAN, bcur);
  add_offsets_kernel<<<NB_SCAN, blk, 0, stream>>>(rowptr, cursor, partials, NN);
  bucket_scatter_kernel<<<(NE + CHUNK - 1) / CHUNK, blk, 0, stream>>>(
      src, dst, ew, bcur, esw, ed, NE);
  fine_fill_kernel<<<edge_grid, blk, 0, stream>>>(esw, ed, cursor, csr, NE);

  // ---- layer 1: GEMM (fp32 features -> bf16 h) ----
  mfma_gemm<512, 64, true><<<gemm_grid, blk, 0, stream>>>(features, W1, hb, NN);
  // ---- layer 1 agg + layer 2 GEMM fused ----
  agg_mm_kernel<64><<<agg_grid, blk, 0, stream>>>(rowptr, deg, csr, hb, b1,
                                                  W2, xb, NN);
  // ---- layer 2 agg + layer 3 GEMM fused ----
  agg_mm_kernel<40><<<agg_grid, blk, 0, stream>>>(rowptr, deg, csr, xb, b2,
                                                  W3, hb, NN);
  // ---- layer 3 agg + bias + log_softmax ----
  agg_lsm_kernel<<<row_grid, blk, 0, stream>>>(rowptr, deg, csr, hb, b3, out,
                                               NN);
}

// Round 3
// 656.855 us; speedup vs baseline: 1.2296x; 1.2296x over previous
//
#include <hip/hip_runtime.h>
#include <hip/hip_bf16.h>
#include <math.h>

#define NN 100000
#define NE 1600000
#define NB_SCAN ((NN + 255) / 256)  // 391
#define NBUK 98                     // dst >> 10, 99999>>10 = 97
#define CHUNK 2048                  // edges per bucket_scatter block
#define NSLOT 78                    // W1:64 + W2:8 + W3:6 fragment slots

typedef __attribute__((ext_vector_type(8))) short bf8_t;   // 8 bf16 = 4 VGPRs
typedef __attribute__((ext_vector_type(4))) float f4_t;    // 4 fp32 acc
typedef __attribute__((ext_vector_type(8))) unsigned short us8_t;  // 16B

__device__ __forceinline__ ushort f2b(float f) {
  __hip_bfloat16 h = __float2bfloat16(f);  // RNE
  return *(ushort*)&h;
}
__device__ __forceinline__ float b2f(ushort u) {
  return __uint_as_float(((unsigned)u) << 16);
}

// ---------------------------------------------------------------------------
// One-time W fragment swizzle: W[K][N] fp32 -> bf16 in MFMA B-frag order.
// slot = (ks*2+s)*NT + t ; element j of lane = W[ks*64+s*32+(lane>>4)*8+j]
//                                               [t*16+(lane&15)]  (0 if col>=N)
// Slot stride = 64 lanes * 8 ushorts = 512 ushorts (1KB).
// Layout: W1 slots [0,64) | W2 [64,72) | W3 [72,78).
// ---------------------------------------------------------------------------
__global__ __launch_bounds__(256) void wconv_kernel(
    const float* __restrict__ W1, const float* __restrict__ W2,
    const float* __restrict__ W3, ushort* __restrict__ out) {
  int g = blockIdx.x * 256 + threadIdx.x;  // slot*64 + lane
  if (g >= NSLOT * 64) return;
  int slot = g >> 6, lane = g & 63;
  const float* W;
  int ks, s, t, N;
  if (slot < 64) {
    W = W1; N = 64; ks = slot >> 3; s = (slot >> 2) & 1; t = slot & 3;
  } else if (slot < 72) {
    int l = slot - 64; W = W2; N = 64; ks = 0; s = (l >> 2) & 1; t = l & 3;
  } else {
    int l = slot - 72; W = W3; N = 40; ks = 0; s = l / 3; t = l % 3;
  }
  int col = t * 16 + (lane & 15);
  int krow = ks * 64 + s * 32 + ((lane >> 4) << 3);
  us8_t o;
#pragma unroll
  for (int j = 0; j < 8; j++)
    o[j] = (col < N) ? f2b(W[(long)(krow + j) * N + col]) : (ushort)0;
  *(us8_t*)&out[(size_t)g * 8] = o;
}

// ---------------------------------------------------------------------------
// Barrier-free direct-fragment MFMA GEMM: Y[M,NCOL] = X[M,KS*64] @ W.
// A-frags loaded straight from global (16 rows x 32B/lane; lanes {r,r+16,
// r+32,r+48} consume one full 128B line of row r). B-frags from the
// pre-swizzled bf16 W (wave-contiguous 1KB per (s,t), L1/L2-resident).
// No LDS, no __syncthreads -> waves pipeline freely.
// ---------------------------------------------------------------------------
template <int KS, int NT, int NCOL, bool XF32>
__global__ __launch_bounds__(256) void gemm_direct(
    const void* __restrict__ Xv, const ushort* __restrict__ Wb,
    ushort* __restrict__ Y, int M) {
  const int tid = threadIdx.x;
  const int wave = tid >> 6;
  const int lane = tid & 63;
  const int K = KS * 64;
  const int row0 = blockIdx.x * 64 + wave * 16;
  int arow = row0 + (lane & 15);
  if (arow >= M) arow = M - 1;  // clamp: loads stay valid, epilogue guards
  const int kcol = (lane >> 4) << 3;

  f4_t acc[NT];
#pragma unroll
  for (int t = 0; t < NT; t++) acc[t] = (f4_t){0.f, 0.f, 0.f, 0.f};

#pragma unroll 2
  for (int ks = 0; ks < KS; ks++) {
#pragma unroll
    for (int s = 0; s < 2; s++) {
      const int kbase = ks * 64 + s * 32 + kcol;
      bf8_t af;
      if (XF32) {
        const float* xp = (const float*)Xv + (long)arow * K + kbase;
        float4 a0 = *(const float4*)xp;
        float4 a1 = *(const float4*)(xp + 4);
        af[0] = (short)f2b(a0.x); af[1] = (short)f2b(a0.y);
        af[2] = (short)f2b(a0.z); af[3] = (short)f2b(a0.w);
        af[4] = (short)f2b(a1.x); af[5] = (short)f2b(a1.y);
        af[6] = (short)f2b(a1.z); af[7] = (short)f2b(a1.w);
      } else {
        af = *(const bf8_t*)((const ushort*)Xv + (long)arow * K + kbase);
      }
#pragma unroll
      for (int t = 0; t < NT; t++) {
        bf8_t bf = *(const bf8_t*)&Wb[(size_t)(((ks * 2 + s) * NT + t) * 64 +
                                               lane) * 8];
        acc[t] = __builtin_amdgcn_mfma_f32_16x16x32_bf16(af, bf, acc[t], 0, 0, 0);
      }
    }
  }
  const int crow0 = row0 + ((lane >> 4) << 2);
  const int ccol = lane & 15;
#pragma unroll
  for (int t = 0; t < NT; t++) {
    int col = ccol + t * 16;
    if (col < NCOL) {
#pragma unroll
      for (int r = 0; r < 4; r++) {
        int row = crow0 + r;
        if (row < M) Y[(long)row * NCOL + col] = f2b(acc[t][r]);
      }
    }
  }
}

// ---------------------------------------------------------------------------
// CSR build: histogram -> scan -> bucket scatter -> fine fill
// ---------------------------------------------------------------------------
__global__ __launch_bounds__(256) void hist_kernel(const int* __restrict__ dst,
                                                   int* __restrict__ deg) {
  int idx = blockIdx.x * 256 + threadIdx.x;
  if (idx < NE / 4) {
    int4 d4 = ((const int4*)dst)[idx];
    atomicAdd(&deg[d4.x], 1);
    atomicAdd(&deg[d4.y], 1);
    atomicAdd(&deg[d4.z], 1);
    atomicAdd(&deg[d4.w], 1);
  }
}

__global__ __launch_bounds__(256) void scan_blocks_kernel(
    const int* __restrict__ deg, int* __restrict__ rowptr,
    int* __restrict__ partials, int n) {
  __shared__ int tmp[256];
  int tid = threadIdx.x;
  int gid = blockIdx.x * 256 + tid;
  int v = (gid < n) ? deg[gid] : 0;
  tmp[tid] = v;
  __syncthreads();
#pragma unroll
  for (int off = 1; off < 256; off <<= 1) {
    int t = (tid >= off) ? tmp[tid - off] : 0;
    __syncthreads();
    tmp[tid] += t;
    __syncthreads();
  }
  if (gid < n) rowptr[gid] = tmp[tid] - v;
  if (tid == 255) partials[blockIdx.x] = tmp[255];
}

// scan partials; then bcur[b] = scanned partials[4b] (== rowptr[b<<10],
// since (b<<10)%256==0 makes the local exclusive prefix zero there).
__global__ __launch_bounds__(64) void scan_partials_bcur_kernel(
    int* __restrict__ p, int n, int* __restrict__ bcur) {
  int lane = threadIdx.x;
  int carry = 0;
  for (int base = 0; base < n; base += 64) {
    int i = base + lane;
    int v = (i < n) ? p[i] : 0;
#pragma unroll
    for (int off = 1; off < 64; off <<= 1) {
      int t = __shfl_up(v, off, 64);
      if (lane >= off) v += t;
    }
    int total = __shfl(v, 63, 64);
    int ex = __shfl_up(v, 1, 64);
    if (lane == 0) ex = 0;
    if (i < n) p[i] = carry + ex;
    carry += total;
  }
  __syncthreads();
  for (int b = lane; b < NBUK; b += 64) bcur[b] = p[4 * b];
}

__global__ __launch_bounds__(256) void add_offsets_kernel(
    int* __restrict__ rowptr, int* __restrict__ cursor,
    const int* __restrict__ partials, int n) {
  int gid = blockIdx.x * 256 + threadIdx.x;
  if (gid < n) {
    int v = rowptr[gid] + partials[blockIdx.x];
    rowptr[gid] = v;
    cursor[gid] = v;
  }
}

// Pass B: group edges by bucket (dst>>10) with block-aggregated reservation.
__global__ __launch_bounds__(256) void bucket_scatter_kernel(
    const int* __restrict__ src, const int* __restrict__ dst,
    const float* __restrict__ ew, int* __restrict__ bcur,
    int2* __restrict__ esw, int* __restrict__ ed, int n) {
  __shared__ int lcnt[NBUK];
  __shared__ int lbase[NBUK];
  const int tid = threadIdx.x;
  const int e0 = blockIdx.x * CHUNK;
  for (int i = tid; i < NBUK; i += 256) lcnt[i] = 0;
  __syncthreads();

  int es[8], ds[8], rk[8];
  float wv[8];
#pragma unroll
  for (int k = 0; k < 8; k++) {
    int e = e0 + k * 256 + tid;
    if (e < n) {
      es[k] = src[e];
      ds[k] = dst[e];
      wv[k] = ew[e];
      rk[k] = atomicAdd(&lcnt[ds[k] >> 10], 1);
    } else {
      ds[k] = -1;
    }
  }
  __syncthreads();
  for (int i = tid; i < NBUK; i += 256)
    lbase[i] = lcnt[i] ? atomicAdd(&bcur[i], lcnt[i]) : 0;
  __syncthreads();
#pragma unroll
  for (int k = 0; k < 8; k++) {
    if (ds[k] >= 0) {
      int p = lbase[ds[k] >> 10] + rk[k];
      esw[p] = make_int2(es[k], __float_as_int(wv[k]));
      ed[p] = ds[k];
    }
  }
}

// Pass C: edges now bucket-grouped; per-node scatter stays inside one
// bucket's <=132KB CSR window -> L2-absorbed writes.
__global__ __launch_bounds__(256) void fine_fill_kernel(
    const int2* __restrict__ esw, const int* __restrict__ ed,
    int* __restrict__ cursor, int2* __restrict__ csr, int n) {
  int i = blockIdx.x * 256 + threadIdx.x;
  if (i < n) {
    int d = ed[i];
    int pos = atomicAdd(&cursor[d], 1);
    csr[pos] = esw[i];
  }
}

// ---------------------------------------------------------------------------
// Pull aggregation D=64, 1 row/wave (max TLP): 8 edges in flight per step.
// ---------------------------------------------------------------------------
template <bool RELU>
__global__ __launch_bounds__(256) void agg64_kernel(
    const int* __restrict__ rowptr, const int* __restrict__ deg,
    const int2* __restrict__ csr, const ushort* __restrict__ H,
    const float* __restrict__ b, ushort* __restrict__ out, int nR) {
  int lane = threadIdx.x & 63;
  int r = blockIdx.x * 4 + (threadIdx.x >> 6);
  if (r >= nR) return;
  int beg = rowptr[r];
  int d = deg[r];
  int g = lane >> 3;
  int sub = lane & 7;
  float acc[8];
#pragma unroll
  for (int k = 0; k < 8; k++) acc[k] = 0.f;

  for (int j0 = 0; j0 < d; j0 += 8) {
    int jj = j0 + g;
    int2 cw = (jj < d) ? csr[beg + jj] : make_int2(0, 0);  // w=0 pad
    float w = __int_as_float(cw.y);
    us8_t hv = *(const us8_t*)&H[(long)cw.x * 64 + sub * 8];
#pragma unroll
    for (int k = 0; k < 8; k++) acc[k] += w * b2f(hv[k]);
  }
#pragma unroll
  for (int off = 8; off < 64; off <<= 1)
#pragma unroll
    for (int k = 0; k < 8; k++) acc[k] += __shfl_xor(acc[k], off, 64);

  if (g == 0) {
    us8_t o;
#pragma unroll
    for (int k = 0; k < 8; k++) {
      float v = acc[k] + b[sub * 8 + k];
      if (RELU) v = fmaxf(v, 0.f);
      o[k] = f2b(v);
    }
    *(us8_t*)&out[(long)r * 64 + sub * 8] = o;
  }
}

// ---------------------------------------------------------------------------
// Layer-3 fused: chunked aggregation (D=40) + bias + log_softmax, fp32 out.
// ---------------------------------------------------------------------------
__global__ __launch_bounds__(256) void agg_lsm_kernel(
    const int* __restrict__ rowptr, const int* __restrict__ deg,
    const int2* __restrict__ csr, const ushort* __restrict__ H,
    const float* __restrict__ b, float* __restrict__ out, int nR) {
  int lane = threadIdx.x & 63;
  int r = blockIdx.x * 4 + (threadIdx.x >> 6);
  if (r >= nR) return;
  int beg = rowptr[r];
  int d = deg[r];
  int g = lane >> 3;
  int sub = lane & 7;
  float acc[8];
#pragma unroll
  for (int k = 0; k < 8; k++) acc[k] = 0.f;

  for (int j0 = 0; j0 < d; j0 += 8) {
    int jj = j0 + g;
    int2 cw = (jj < d) ? csr[beg + jj] : make_int2(0, 0);
    float w = __int_as_float(cw.y);
    if (sub < 5) {
      us8_t hv = *(const us8_t*)&H[(long)cw.x * 40 + sub * 8];
#pragma unroll
      for (int k = 0; k < 8; k++) acc[k] += w * b2f(hv[k]);
    }
  }
#pragma unroll
  for (int off = 8; off < 64; off <<= 1)
#pragma unroll
    for (int k = 0; k < 8; k++) acc[k] += __shfl_xor(acc[k], off, 64);

  float v[8];
  float m = -INFINITY, s = 0.f;
  if (sub < 5) {
#pragma unroll
    for (int k = 0; k < 8; k++) {
      v[k] = acc[k] + b[sub * 8 + k];
      m = fmaxf(m, v[k]);
    }
  }
#pragma unroll
  for (int off = 1; off < 8; off <<= 1) m = fmaxf(m, __shfl_xor(m, off, 64));
  if (sub < 5) {
#pragma unroll
    for (int k = 0; k < 8; k++) s += __expf(v[k] - m);
  }
#pragma unroll
  for (int off = 1; off < 8; off <<= 1) s += __shfl_xor(s, off, 64);

  if (g == 0 && sub < 5) {
    float lg = m + __logf(s);
    float4 o0 = make_float4(v[0] - lg, v[1] - lg, v[2] - lg, v[3] - lg);
    float4 o1 = make_float4(v[4] - lg, v[5] - lg, v[6] - lg, v[7] - lg);
    *(float4*)&out[(long)r * 40 + sub * 8] = o0;
    *(float4*)&out[(long)r * 40 + sub * 8 + 4] = o1;
  }
}

extern "C" void kernel_launch(void* const* d_in, const int* in_sizes, int n_in,
                              void* d_out, int out_size, void* d_ws,
                              size_t ws_size, hipStream_t stream) {
  const int* edge_index = (const int*)d_in[0];
  const float* features = (const float*)d_in[1];
  const float* ew = (const float*)d_in[2];
  const float* W1 = (const float*)d_in[3];
  const float* b1 = (const float*)d_in[4];
  const float* W2 = (const float*)d_in[5];
  const float* b2 = (const float*)d_in[6];
  const float* W3 = (const float*)d_in[7];
  const float* b3 = (const float*)d_in[8];
  float* out = (float*)d_out;
  const int* src = edge_index;
  const int* dst = edge_index + NE;

  // workspace layout
  char* p = (char*)d_ws;
  int2* csr = (int2*)p;              p += (size_t)NE * 8;       // 12.8 MB
  int2* esw = (int2*)p;              p += (size_t)NE * 8;       // 12.8 MB
  int* ed = (int*)p;                 p += (size_t)NE * 4;       // 6.4 MB
  int* deg = (int*)p;                p += (size_t)NN * 4;
  int* rowptr = (int*)p;             p += (size_t)NN * 4;
  int* cursor = (int*)p;             p += (size_t)NN * 4;
  int* partials = (int*)p;           p += 1024 * 4;
  int* bcur = (int*)p;               p += 128 * 4;
  ushort* wswz = (ushort*)p;         p += (size_t)NSLOT * 512 * 2;  // 78 KB
  ushort* hb = (ushort*)p;           p += (size_t)NN * 64 * 2;  // layer buffers
  ushort* xb = (ushort*)p;           p += (size_t)NN * 64 * 2;

  dim3 blk(256);
  const int gemm_grid = (NN + 63) / 64;
  const int edge_grid = (NE + 255) / 256;
  const int hist_grid = (NE / 4 + 255) / 256;
  const int row_grid = (NN + 3) / 4;

  // ---- one-time W fragment swizzle (tiny) ----
  wconv_kernel<<<(NSLOT * 64 + 255) / 256, blk, 0, stream>>>(W1, W2, W3, wswz);

  // ---- CSR build (by dst) ----
  hipMemsetAsync(deg, 0, NN * sizeof(int), stream);
  hist_kernel<<<hist_grid, blk, 0, stream>>>(dst, deg);
  scan_blocks_kernel<<<NB_SCAN, blk, 0, stream>>>(deg, rowptr, partials, NN);
  scan_partials_bcur_kernel<<<1, 64, 0, stream>>>(partials, NB_SCAN, bcur);
  add_offsets_kernel<<<NB_SCAN, blk, 0, stream>>>(rowptr, cursor, partials, NN);
  bucket_scatter_kernel<<<(NE + CHUNK - 1) / CHUNK, blk, 0, stream>>>(
      src, dst, ew, bcur, esw, ed, NE);
  fine_fill_kernel<<<edge_grid, blk, 0, stream>>>(esw, ed, cursor, csr, NE);

  // ---- layer 1 ----
  gemm_direct<8, 4, 64, true><<<gemm_grid, blk, 0, stream>>>(features, wswz,
                                                             hb, NN);
  agg64_kernel<true><<<row_grid, blk, 0, stream>>>(rowptr, deg, csr, hb, b1,
                                                   xb, NN);
  // ---- layer 2 ----
  gemm_direct<1, 4, 64, false><<<gemm_grid, blk, 0, stream>>>(
      xb, wswz + (size_t)64 * 512, hb, NN);
  agg64_kernel<true><<<row_grid, blk, 0, stream>>>(rowptr, deg, csr, hb, b2,
                                                   xb, NN);
  // ---- layer 3 ----
  gemm_direct<1, 3, 40, false><<<gemm_grid, blk, 0, stream>>>(
      xb, wswz + (size_t)72 * 512, hb, NN);
  agg_lsm_kernel<<<row_grid, blk, 0, stream>>>(rowptr, deg, csr, hb, b3, out,
                                               NN);
}

// Round 4
// 592.317 us; speedup vs baseline: 1.3636x; 1.1090x over previous
//
#include <hip/hip_runtime.h>
#include <hip/hip_bf16.h>
#include <math.h>

#define NN 100000
#define NE 1600000
#define NBUK 391        // dst >> 8 buckets (256 nodes each), 99999>>8 = 390
#define CHUNK 2048      // edges per bucket_scatter block
#define HCHUNK 4096     // edges per histB block
#define NSLOT 78        // W1:64 + W2:8 + W3:6 fragment slots

typedef __attribute__((ext_vector_type(8))) short bf8_t;   // 8 bf16 = 4 VGPRs
typedef __attribute__((ext_vector_type(4))) float f4_t;    // 4 fp32 acc
typedef __attribute__((ext_vector_type(8))) unsigned short us8_t;  // 16B

__device__ __forceinline__ ushort f2b(float f) {
  __hip_bfloat16 h = __float2bfloat16(f);  // RNE
  return *(ushort*)&h;
}
__device__ __forceinline__ float b2f(ushort u) {
  return __uint_as_float(((unsigned)u) << 16);
}

// ---------------------------------------------------------------------------
// One-time W fragment swizzle: W[K][N] fp32 -> bf16 in MFMA B-frag order.
// slot = (ks*2+s)*NT + t ; element j of lane = W[ks*64+s*32+(lane>>4)*8+j]
//                                               [t*16+(lane&15)]  (0 if col>=N)
// Layout: W1 slots [0,64) | W2 [64,72) | W3 [72,78). Slot stride 512 ushorts.
// ---------------------------------------------------------------------------
__global__ __launch_bounds__(256) void wconv_kernel(
    const float* __restrict__ W1, const float* __restrict__ W2,
    const float* __restrict__ W3, ushort* __restrict__ out) {
  int g = blockIdx.x * 256 + threadIdx.x;  // slot*64 + lane
  if (g >= NSLOT * 64) return;
  int slot = g >> 6, lane = g & 63;
  const float* W;
  int ks, s, t, N;
  if (slot < 64) {
    W = W1; N = 64; ks = slot >> 3; s = (slot >> 2) & 1; t = slot & 3;
  } else if (slot < 72) {
    int l = slot - 64; W = W2; N = 64; ks = 0; s = (l >> 2) & 1; t = l & 3;
  } else {
    int l = slot - 72; W = W3; N = 40; ks = 0; s = l / 3; t = l % 3;
  }
  int col = t * 16 + (lane & 15);
  int krow = ks * 64 + s * 32 + ((lane >> 4) << 3);
  us8_t o;
#pragma unroll
  for (int j = 0; j < 8; j++)
    o[j] = (col < N) ? f2b(W[(long)(krow + j) * N + col]) : (ushort)0;
  *(us8_t*)&out[(size_t)g * 8] = o;
}

// ---------------------------------------------------------------------------
// Barrier-free direct-fragment MFMA GEMM: Y[M,NCOL] = X[M,KS*64] @ W.
// ---------------------------------------------------------------------------
template <int KS, int NT, int NCOL, bool XF32>
__global__ __launch_bounds__(256) void gemm_direct(
    const void* __restrict__ Xv, const ushort* __restrict__ Wb,
    ushort* __restrict__ Y, int M) {
  const int tid = threadIdx.x;
  const int wave = tid >> 6;
  const int lane = tid & 63;
  const int K = KS * 64;
  const int row0 = blockIdx.x * 64 + wave * 16;
  int arow = row0 + (lane & 15);
  if (arow >= M) arow = M - 1;  // clamp: loads stay valid, epilogue guards
  const int kcol = (lane >> 4) << 3;

  f4_t acc[NT];
#pragma unroll
  for (int t = 0; t < NT; t++) acc[t] = (f4_t){0.f, 0.f, 0.f, 0.f};

#pragma unroll 2
  for (int ks = 0; ks < KS; ks++) {
#pragma unroll
    for (int s = 0; s < 2; s++) {
      const int kbase = ks * 64 + s * 32 + kcol;
      bf8_t af;
      if (XF32) {
        const float* xp = (const float*)Xv + (long)arow * K + kbase;
        float4 a0 = *(const float4*)xp;
        float4 a1 = *(const float4*)(xp + 4);
        af[0] = (short)f2b(a0.x); af[1] = (short)f2b(a0.y);
        af[2] = (short)f2b(a0.z); af[3] = (short)f2b(a0.w);
        af[4] = (short)f2b(a1.x); af[5] = (short)f2b(a1.y);
        af[6] = (short)f2b(a1.z); af[7] = (short)f2b(a1.w);
      } else {
        af = *(const bf8_t*)((const ushort*)Xv + (long)arow * K + kbase);
      }
#pragma unroll
      for (int t = 0; t < NT; t++) {
        bf8_t bf = *(const bf8_t*)&Wb[(size_t)(((ks * 2 + s) * NT + t) * 64 +
                                               lane) * 8];
        acc[t] = __builtin_amdgcn_mfma_f32_16x16x32_bf16(af, bf, acc[t], 0, 0, 0);
      }
    }
  }
  const int crow0 = row0 + ((lane >> 4) << 2);
  const int ccol = lane & 15;
#pragma unroll
  for (int t = 0; t < NT; t++) {
    int col = ccol + t * 16;
    if (col < NCOL) {
#pragma unroll
      for (int r = 0; r < 4; r++) {
        int row = crow0 + r;
        if (row < M) Y[(long)row * NCOL + col] = f2b(acc[t][r]);
      }
    }
  }
}

// ---------------------------------------------------------------------------
// CSR build v2 — near-zero global atomics:
//  A) histB: LDS bucket histogram (dst>>8), 391 global adds per block
//  B) scan_bkoff: 1-block scan of 391 bucket counts -> bkoff, bcur
//  C) bucket_scatter: group edges by bucket (block-aggregated reservation)
//  D) finalize: block-per-bucket; LDS node-hist -> LDS scan -> rowptr/deg
//     -> LDS-cursor scatter into csr. No per-edge global atomics anywhere.
// ---------------------------------------------------------------------------
__global__ __launch_bounds__(256) void histB_kernel(const int* __restrict__ dst,
                                                    int* __restrict__ bkcnt) {
  __shared__ int lh[NBUK];
  const int tid = threadIdx.x;
  for (int i = tid; i < NBUK; i += 256) lh[i] = 0;
  __syncthreads();
  const int q0 = blockIdx.x * (HCHUNK / 4);
#pragma unroll
  for (int k = 0; k < HCHUNK / 1024; k++) {
    int idx = q0 + k * 256 + tid;
    if (idx < NE / 4) {
      int4 d4 = ((const int4*)dst)[idx];
      atomicAdd(&lh[d4.x >> 8], 1);
      atomicAdd(&lh[d4.y >> 8], 1);
      atomicAdd(&lh[d4.z >> 8], 1);
      atomicAdd(&lh[d4.w >> 8], 1);
    }
  }
  __syncthreads();
  for (int i = tid; i < NBUK; i += 256)
    if (lh[i]) atomicAdd(&bkcnt[i], lh[i]);
}

__global__ __launch_bounds__(64) void scan_bkoff_kernel(
    const int* __restrict__ bkcnt, int* __restrict__ bkoff,
    int* __restrict__ bcur) {
  int lane = threadIdx.x;
  int carry = 0;
  for (int base = 0; base < NBUK; base += 64) {
    int i = base + lane;
    int v = (i < NBUK) ? bkcnt[i] : 0;
#pragma unroll
    for (int off = 1; off < 64; off <<= 1) {
      int t = __shfl_up(v, off, 64);
      if (lane >= off) v += t;
    }
    int total = __shfl(v, 63, 64);
    int ex = __shfl_up(v, 1, 64);
    if (lane == 0) ex = 0;
    if (i < NBUK) {
      bkoff[i] = carry + ex;
      bcur[i] = carry + ex;
    }
    carry += total;
  }
  if (lane == 0) bkoff[NBUK] = carry;  // == NE
}

// Pass C: group edges by bucket (dst>>8) with block-aggregated reservation.
__global__ __launch_bounds__(256) void bucket_scatter_kernel(
    const int* __restrict__ src, const int* __restrict__ dst,
    const float* __restrict__ ew, int* __restrict__ bcur,
    int2* __restrict__ esw, int* __restrict__ ed, int n) {
  __shared__ int lcnt[NBUK];
  __shared__ int lbase[NBUK];
  const int tid = threadIdx.x;
  const int e0 = blockIdx.x * CHUNK;
  for (int i = tid; i < NBUK; i += 256) lcnt[i] = 0;
  __syncthreads();

  int es[8], ds[8], rk[8];
  float wv[8];
#pragma unroll
  for (int k = 0; k < 8; k++) {
    int e = e0 + k * 256 + tid;
    if (e < n) {
      es[k] = src[e];
      ds[k] = dst[e];
      wv[k] = ew[e];
      rk[k] = atomicAdd(&lcnt[ds[k] >> 8], 1);
    } else {
      ds[k] = -1;
    }
  }
  __syncthreads();
  for (int i = tid; i < NBUK; i += 256)
    lbase[i] = lcnt[i] ? atomicAdd(&bcur[i], lcnt[i]) : 0;
  __syncthreads();
#pragma unroll
  for (int k = 0; k < 8; k++) {
    if (ds[k] >= 0) {
      int p = lbase[ds[k] >> 8] + rk[k];
      esw[p] = make_int2(es[k], __float_as_int(wv[k]));
      ed[p] = ds[k];
    }
  }
}

// Pass D: block b owns bucket b (256 nodes, ~4K edges). Everything local.
__global__ __launch_bounds__(256) void finalize_kernel(
    const int* __restrict__ bkoff, const int2* __restrict__ esw,
    const int* __restrict__ ed, int* __restrict__ rowptr,
    int* __restrict__ deg, int2* __restrict__ csr) {
  __shared__ int ldeg[256];
  __shared__ int lcur[256];
  const int b = blockIdx.x;
  const int tid = threadIdx.x;
  const int e0 = bkoff[b], e1 = bkoff[b + 1];

  ldeg[tid] = 0;
  __syncthreads();
  for (int e = e0 + tid; e < e1; e += 256) atomicAdd(&ldeg[ed[e] & 255], 1);
  __syncthreads();
  const int v = ldeg[tid];
  lcur[tid] = v;
  __syncthreads();
#pragma unroll
  for (int off = 1; off < 256; off <<= 1) {
    int t = (tid >= off) ? lcur[tid - off] : 0;
    __syncthreads();
    lcur[tid] += t;
    __syncthreads();
  }
  const int excl = lcur[tid] - v;  // exclusive local prefix
  const int node = b * 256 + tid;
  if (node < NN) {
    rowptr[node] = e0 + excl;
    deg[node] = v;
  }
  __syncthreads();
  lcur[tid] = e0 + excl;  // absolute write cursor for this node
  __syncthreads();
  for (int e = e0 + tid; e < e1; e += 256) {
    int pos = atomicAdd(&lcur[ed[e] & 255], 1);
    csr[pos] = esw[e];
  }
}

// ---------------------------------------------------------------------------
// Pull aggregation D=64, 1 row/wave (max TLP): 8 edges in flight per step.
// ---------------------------------------------------------------------------
template <bool RELU>
__global__ __launch_bounds__(256) void agg64_kernel(
    const int* __restrict__ rowptr, const int* __restrict__ deg,
    const int2* __restrict__ csr, const ushort* __restrict__ H,
    const float* __restrict__ b, ushort* __restrict__ out, int nR) {
  int lane = threadIdx.x & 63;
  int r = blockIdx.x * 4 + (threadIdx.x >> 6);
  if (r >= nR) return;
  int beg = rowptr[r];
  int d = deg[r];
  int g = lane >> 3;
  int sub = lane & 7;
  float acc[8];
#pragma unroll
  for (int k = 0; k < 8; k++) acc[k] = 0.f;

  for (int j0 = 0; j0 < d; j0 += 8) {
    int jj = j0 + g;
    int2 cw = (jj < d) ? csr[beg + jj] : make_int2(0, 0);  // w=0 pad
    float w = __int_as_float(cw.y);
    us8_t hv = *(const us8_t*)&H[(long)cw.x * 64 + sub * 8];
#pragma unroll
    for (int k = 0; k < 8; k++) acc[k] += w * b2f(hv[k]);
  }
#pragma unroll
  for (int off = 8; off < 64; off <<= 1)
#pragma unroll
    for (int k = 0; k < 8; k++) acc[k] += __shfl_xor(acc[k], off, 64);

  if (g == 0) {
    us8_t o;
#pragma unroll
    for (int k = 0; k < 8; k++) {
      float v = acc[k] + b[sub * 8 + k];
      if (RELU) v = fmaxf(v, 0.f);
      o[k] = f2b(v);
    }
    *(us8_t*)&out[(long)r * 64 + sub * 8] = o;
  }
}

// ---------------------------------------------------------------------------
// Layer-3 fused: chunked aggregation (D=40) + bias + log_softmax, fp32 out.
// ---------------------------------------------------------------------------
__global__ __launch_bounds__(256) void agg_lsm_kernel(
    const int* __restrict__ rowptr, const int* __restrict__ deg,
    const int2* __restrict__ csr, const ushort* __restrict__ H,
    const float* __restrict__ b, float* __restrict__ out, int nR) {
  int lane = threadIdx.x & 63;
  int r = blockIdx.x * 4 + (threadIdx.x >> 6);
  if (r >= nR) return;
  int beg = rowptr[r];
  int d = deg[r];
  int g = lane >> 3;
  int sub = lane & 7;
  float acc[8];
#pragma unroll
  for (int k = 0; k < 8; k++) acc[k] = 0.f;

  for (int j0 = 0; j0 < d; j0 += 8) {
    int jj = j0 + g;
    int2 cw = (jj < d) ? csr[beg + jj] : make_int2(0, 0);
    float w = __int_as_float(cw.y);
    if (sub < 5) {
      us8_t hv = *(const us8_t*)&H[(long)cw.x * 40 + sub * 8];
#pragma unroll
      for (int k = 0; k < 8; k++) acc[k] += w * b2f(hv[k]);
    }
  }
#pragma unroll
  for (int off = 8; off < 64; off <<= 1)
#pragma unroll
    for (int k = 0; k < 8; k++) acc[k] += __shfl_xor(acc[k], off, 64);

  float v[8];
  float m = -INFINITY, s = 0.f;
  if (sub < 5) {
#pragma unroll
    for (int k = 0; k < 8; k++) {
      v[k] = acc[k] + b[sub * 8 + k];
      m = fmaxf(m, v[k]);
    }
  }
#pragma unroll
  for (int off = 1; off < 8; off <<= 1) m = fmaxf(m, __shfl_xor(m, off, 64));
  if (sub < 5) {
#pragma unroll
    for (int k = 0; k < 8; k++) s += __expf(v[k] - m);
  }
#pragma unroll
  for (int off = 1; off < 8; off <<= 1) s += __shfl_xor(s, off, 64);

  if (g == 0 && sub < 5) {
    float lg = m + __logf(s);
    float4 o0 = make_float4(v[0] - lg, v[1] - lg, v[2] - lg, v[3] - lg);
    float4 o1 = make_float4(v[4] - lg, v[5] - lg, v[6] - lg, v[7] - lg);
    *(float4*)&out[(long)r * 40 + sub * 8] = o0;
    *(float4*)&out[(long)r * 40 + sub * 8 + 4] = o1;
  }
}

extern "C" void kernel_launch(void* const* d_in, const int* in_sizes, int n_in,
                              void* d_out, int out_size, void* d_ws,
                              size_t ws_size, hipStream_t stream) {
  const int* edge_index = (const int*)d_in[0];
  const float* features = (const float*)d_in[1];
  const float* ew = (const float*)d_in[2];
  const float* W1 = (const float*)d_in[3];
  const float* b1 = (const float*)d_in[4];
  const float* W2 = (const float*)d_in[5];
  const float* b2 = (const float*)d_in[6];
  const float* W3 = (const float*)d_in[7];
  const float* b3 = (const float*)d_in[8];
  float* out = (float*)d_out;
  const int* src = edge_index;
  const int* dst = edge_index + NE;

  // workspace layout
  char* p = (char*)d_ws;
  int2* csr = (int2*)p;              p += (size_t)NE * 8;       // 12.8 MB
  int2* esw = (int2*)p;              p += (size_t)NE * 8;       // 12.8 MB
  int* ed = (int*)p;                 p += (size_t)NE * 4;       // 6.4 MB
  int* deg = (int*)p;                p += (size_t)NN * 4;
  int* rowptr = (int*)p;             p += (size_t)NN * 4;
  int* bkcnt = (int*)p;              p += 512 * 4;
  int* bkoff = (int*)p;              p += 512 * 4;
  int* bcur = (int*)p;               p += 512 * 4;
  ushort* wswz = (ushort*)p;         p += (size_t)NSLOT * 512 * 2;  // 78 KB
  ushort* hb = (ushort*)p;           p += (size_t)NN * 64 * 2;  // layer buffers
  ushort* xb = (ushort*)p;           p += (size_t)NN * 64 * 2;

  dim3 blk(256);
  const int gemm_grid = (NN + 63) / 64;
  const int row_grid = (NN + 3) / 4;

  // ---- one-time W fragment swizzle (tiny) ----
  wconv_kernel<<<(NSLOT * 64 + 255) / 256, blk, 0, stream>>>(W1, W2, W3, wswz);

  // ---- CSR build v2 (by dst), near-zero global atomics ----
  hipMemsetAsync(bkcnt, 0, NBUK * sizeof(int), stream);
  histB_kernel<<<(NE + HCHUNK - 1) / HCHUNK, blk, 0, stream>>>(dst, bkcnt);
  scan_bkoff_kernel<<<1, 64, 0, stream>>>(bkcnt, bkoff, bcur);
  bucket_scatter_kernel<<<(NE + CHUNK - 1) / CHUNK, blk, 0, stream>>>(
      src, dst, ew, bcur, esw, ed, NE);
  finalize_kernel<<<NBUK, blk, 0, stream>>>(bkoff, esw, ed, rowptr, deg, csr);

  // ---- layer 1 ----
  gemm_direct<8, 4, 64, true><<<gemm_grid, blk, 0, stream>>>(features, wswz,
                                                             hb, NN);
  agg64_kernel<true><<<row_grid, blk, 0, stream>>>(rowptr, deg, csr, hb, b1,
                                                   xb, NN);
  // ---- layer 2 ----
  gemm_direct<1, 4, 64, false><<<gemm_grid, blk, 0, stream>>>(
      xb, wswz + (size_t)64 * 512, hb, NN);
  agg64_kernel<true><<<row_grid, blk, 0, stream>>>(rowptr, deg, csr, hb, b2,
                                                   xb, NN);
  // ---- layer 3 ----
  gemm_direct<1, 3, 40, false><<<gemm_grid, blk, 0, stream>>>(
      xb, wswz + (size_t)72 * 512, hb, NN);
  agg_lsm_kernel<<<row_grid, blk, 0, stream>>>(rowptr, deg, csr, hb, b3, out,
                                               NN);
}

// Round 5
// 563.335 us; speedup vs baseline: 1.4338x; 1.0514x over previous
//
#include <hip/hip_runtime.h>
#include <hip/hip_bf16.h>
#include <math.h>

#define NN 100000
#define NE 1600000
#define NBUK 391        // dst >> 8 buckets (256 nodes each), 99999>>8 = 390
#define CHUNK 4096      // edges per bucket_scatter block
#define HCHUNK 4096     // edges per histB block
#define NSLOT 78        // W1:64 + W2:8 + W3:6 fragment slots
#define SRCMASK 0xFFFFF // src in bits [0,20), dst&255 in bits [20,28)

typedef __attribute__((ext_vector_type(8))) short bf8_t;   // 8 bf16 = 4 VGPRs
typedef __attribute__((ext_vector_type(4))) float f4_t;    // 4 fp32 acc
typedef __attribute__((ext_vector_type(8))) unsigned short us8_t;  // 16B

__device__ __forceinline__ ushort f2b(float f) {
  __hip_bfloat16 h = __float2bfloat16(f);  // RNE
  return *(ushort*)&h;
}
__device__ __forceinline__ float b2f(ushort u) {
  return __uint_as_float(((unsigned)u) << 16);
}

// ---------------------------------------------------------------------------
// One-time W fragment swizzle: W[K][N] fp32 -> bf16 in MFMA B-frag order.
// slot = (ks*2+s)*NT + t ; element j of lane = W[ks*64+s*32+(lane>>4)*8+j]
//                                               [t*16+(lane&15)]  (0 if col>=N)
// Layout: W1 slots [0,64) | W2 [64,72) | W3 [72,78). Slot stride 512 ushorts.
// ---------------------------------------------------------------------------
__global__ __launch_bounds__(256) void wconv_kernel(
    const float* __restrict__ W1, const float* __restrict__ W2,
    const float* __restrict__ W3, ushort* __restrict__ out) {
  int g = blockIdx.x * 256 + threadIdx.x;  // slot*64 + lane
  if (g >= NSLOT * 64) return;
  int slot = g >> 6, lane = g & 63;
  const float* W;
  int ks, s, t, N;
  if (slot < 64) {
    W = W1; N = 64; ks = slot >> 3; s = (slot >> 2) & 1; t = slot & 3;
  } else if (slot < 72) {
    int l = slot - 64; W = W2; N = 64; ks = 0; s = (l >> 2) & 1; t = l & 3;
  } else {
    int l = slot - 72; W = W3; N = 40; ks = 0; s = l / 3; t = l % 3;
  }
  int col = t * 16 + (lane & 15);
  int krow = ks * 64 + s * 32 + ((lane >> 4) << 3);
  us8_t o;
#pragma unroll
  for (int j = 0; j < 8; j++)
    o[j] = (col < N) ? f2b(W[(long)(krow + j) * N + col]) : (ushort)0;
  *(us8_t*)&out[(size_t)g * 8] = o;
}

// ---------------------------------------------------------------------------
// Barrier-free direct-fragment MFMA GEMM: Y[M,NCOL] = X[M,KS*64] @ W.
// ---------------------------------------------------------------------------
template <int KS, int NT, int NCOL, bool XF32>
__global__ __launch_bounds__(256) void gemm_direct(
    const void* __restrict__ Xv, const ushort* __restrict__ Wb,
    ushort* __restrict__ Y, int M) {
  const int tid = threadIdx.x;
  const int wave = tid >> 6;
  const int lane = tid & 63;
  const int K = KS * 64;
  const int row0 = blockIdx.x * 64 + wave * 16;
  int arow = row0 + (lane & 15);
  if (arow >= M) arow = M - 1;  // clamp: loads stay valid, epilogue guards
  const int kcol = (lane >> 4) << 3;

  f4_t acc[NT];
#pragma unroll
  for (int t = 0; t < NT; t++) acc[t] = (f4_t){0.f, 0.f, 0.f, 0.f};

#pragma unroll 2
  for (int ks = 0; ks < KS; ks++) {
#pragma unroll
    for (int s = 0; s < 2; s++) {
      const int kbase = ks * 64 + s * 32 + kcol;
      bf8_t af;
      if (XF32) {
        const float* xp = (const float*)Xv + (long)arow * K + kbase;
        float4 a0 = *(const float4*)xp;
        float4 a1 = *(const float4*)(xp + 4);
        af[0] = (short)f2b(a0.x); af[1] = (short)f2b(a0.y);
        af[2] = (short)f2b(a0.z); af[3] = (short)f2b(a0.w);
        af[4] = (short)f2b(a1.x); af[5] = (short)f2b(a1.y);
        af[6] = (short)f2b(a1.z); af[7] = (short)f2b(a1.w);
      } else {
        af = *(const bf8_t*)((const ushort*)Xv + (long)arow * K + kbase);
      }
#pragma unroll
      for (int t = 0; t < NT; t++) {
        bf8_t bf = *(const bf8_t*)&Wb[(size_t)(((ks * 2 + s) * NT + t) * 64 +
                                               lane) * 8];
        acc[t] = __builtin_amdgcn_mfma_f32_16x16x32_bf16(af, bf, acc[t], 0, 0, 0);
      }
    }
  }
  const int crow0 = row0 + ((lane >> 4) << 2);
  const int ccol = lane & 15;
#pragma unroll
  for (int t = 0; t < NT; t++) {
    int col = ccol + t * 16;
    if (col < NCOL) {
#pragma unroll
      for (int r = 0; r < 4; r++) {
        int row = crow0 + r;
        if (row < M) Y[(long)row * NCOL + col] = f2b(acc[t][r]);
      }
    }
  }
}

// ---------------------------------------------------------------------------
// CSR build v3 — near-zero global atomics AND coalesced scatter:
//  A) histB: LDS bucket histogram (dst>>8)
//  B) scan_bkoff: 1-block scan of bucket counts -> bkoff, bcur
//  C) bucket_scatter: block-local count -> scan -> reserve -> LDS reorder
//     -> sequential write-out (consecutive threads hit consecutive addrs)
//  D) finalize: block-per-bucket; LDS node-hist -> scan -> rowptr/deg ->
//     LDS-cursor scatter into csr (src|dstlow packed stays packed)
// ---------------------------------------------------------------------------
__global__ __launch_bounds__(256) void histB_kernel(const int* __restrict__ dst,
                                                    int* __restrict__ bkcnt) {
  __shared__ int lh[NBUK];
  const int tid = threadIdx.x;
  for (int i = tid; i < NBUK; i += 256) lh[i] = 0;
  __syncthreads();
  const int q0 = blockIdx.x * (HCHUNK / 4);
#pragma unroll
  for (int k = 0; k < HCHUNK / 1024; k++) {
    int idx = q0 + k * 256 + tid;
    if (idx < NE / 4) {
      int4 d4 = ((const int4*)dst)[idx];
      atomicAdd(&lh[d4.x >> 8], 1);
      atomicAdd(&lh[d4.y >> 8], 1);
      atomicAdd(&lh[d4.z >> 8], 1);
      atomicAdd(&lh[d4.w >> 8], 1);
    }
  }
  __syncthreads();
  for (int i = tid; i < NBUK; i += 256)
    if (lh[i]) atomicAdd(&bkcnt[i], lh[i]);
}

__global__ __launch_bounds__(64) void scan_bkoff_kernel(
    const int* __restrict__ bkcnt, int* __restrict__ bkoff,
    int* __restrict__ bcur) {
  int lane = threadIdx.x;
  int carry = 0;
  for (int base = 0; base < NBUK; base += 64) {
    int i = base + lane;
    int v = (i < NBUK) ? bkcnt[i] : 0;
#pragma unroll
    for (int off = 1; off < 64; off <<= 1) {
      int t = __shfl_up(v, off, 64);
      if (lane >= off) v += t;
    }
    int total = __shfl(v, 63, 64);
    int ex = __shfl_up(v, 1, 64);
    if (lane == 0) ex = 0;
    if (i < NBUK) {
      bkoff[i] = carry + ex;
      bcur[i] = carry + ex;
    }
    carry += total;
  }
  if (lane == 0) bkoff[NBUK] = carry;  // == NE
}

// Pass C: block-local counting sort by bucket, then coalesced run write-out.
__global__ __launch_bounds__(256) void bucket_scatter_kernel(
    const int* __restrict__ src, const int* __restrict__ dst,
    const float* __restrict__ ew, int* __restrict__ bcur,
    int2* __restrict__ esw, int n) {
  __shared__ int lcnt[NBUK];    // counts, then rank cursors
  __shared__ int lofs[NBUK];    // local exclusive scan
  __shared__ int gbase[NBUK];   // reserved global base per bucket
  __shared__ int2 stage[CHUNK]; // 32KB bucket-ordered payload
  __shared__ ushort sbk[CHUNK]; // 8KB bucket id per slot
  const int tid = threadIdx.x;
  const int e0 = blockIdx.x * CHUNK;
  const int n1 = min(CHUNK, n - e0);

  for (int i = tid; i < NBUK; i += 256) lcnt[i] = 0;
  __syncthreads();
  // phase 1: count
#pragma unroll
  for (int k = 0; k < CHUNK / 256; k++) {
    int e = e0 + k * 256 + tid;
    if (e < n) atomicAdd(&lcnt[dst[e] >> 8], 1);
  }
  __syncthreads();
  // phase 2: wave-0 scans lcnt -> lofs (exclusive)
  if (tid < 64) {
    int lane = tid;
    int carry = 0;
    for (int base = 0; base < NBUK; base += 64) {
      int i = base + lane;
      int v = (i < NBUK) ? lcnt[i] : 0;
#pragma unroll
      for (int off = 1; off < 64; off <<= 1) {
        int t = __shfl_up(v, off, 64);
        if (lane >= off) v += t;
      }
      int total = __shfl(v, 63, 64);
      int ex = __shfl_up(v, 1, 64);
      if (lane == 0) ex = 0;
      if (i < NBUK) lofs[i] = carry + ex;
      carry += total;
    }
  }
  __syncthreads();
  // phase 3: reserve global bases; reset counts for rank pass
  for (int i = tid; i < NBUK; i += 256) {
    int c = lcnt[i];
    gbase[i] = c ? atomicAdd(&bcur[i], c) : 0;
    lcnt[i] = 0;
  }
  __syncthreads();
  // phase 4: rank + stage into LDS, bucket-grouped
#pragma unroll
  for (int k = 0; k < CHUNK / 256; k++) {
    int e = e0 + k * 256 + tid;
    if (e < n) {
      int d = dst[e];
      int bk = d >> 8;
      int rk = atomicAdd(&lcnt[bk], 1);
      int slot = lofs[bk] + rk;
      stage[slot] = make_int2(src[e] | ((d & 255) << 20),
                              __float_as_int(ew[e]));
      sbk[slot] = (ushort)bk;
    }
  }
  __syncthreads();
  // phase 5: sequential write-out (runs are contiguous per bucket)
  for (int i = tid; i < n1; i += 256) {
    int bk = sbk[i];
    esw[gbase[bk] + (i - lofs[bk])] = stage[i];
  }
}

// Pass D: block b owns bucket b (256 nodes, ~4K edges). Everything local.
__global__ __launch_bounds__(256) void finalize_kernel(
    const int* __restrict__ bkoff, const int2* __restrict__ esw,
    int* __restrict__ rowptr, int* __restrict__ deg, int2* __restrict__ csr) {
  __shared__ int ldeg[256];
  __shared__ int lcur[256];
  const int b = blockIdx.x;
  const int tid = threadIdx.x;
  const int e0 = bkoff[b], e1 = bkoff[b + 1];

  ldeg[tid] = 0;
  __syncthreads();
  for (int e = e0 + tid; e < e1; e += 256)
    atomicAdd(&ldeg[(esw[e].x >> 20) & 255], 1);
  __syncthreads();
  const int v = ldeg[tid];
  lcur[tid] = v;
  __syncthreads();
#pragma unroll
  for (int off = 1; off < 256; off <<= 1) {
    int t = (tid >= off) ? lcur[tid - off] : 0;
    __syncthreads();
    lcur[tid] += t;
    __syncthreads();
  }
  const int excl = lcur[tid] - v;  // exclusive local prefix
  const int node = b * 256 + tid;
  if (node < NN) {
    rowptr[node] = e0 + excl;
    deg[node] = v;
  }
  __syncthreads();
  lcur[tid] = e0 + excl;  // absolute write cursor for this node
  __syncthreads();
  for (int e = e0 + tid; e < e1; e += 256) {
    int2 x = esw[e];
    int pos = atomicAdd(&lcur[(x.x >> 20) & 255], 1);
    csr[pos] = x;  // stays packed; agg kernels mask with SRCMASK
  }
}

// ---------------------------------------------------------------------------
// Pull aggregation D=64, 1 row/wave (max TLP): 8 edges in flight per step.
// ---------------------------------------------------------------------------
template <bool RELU>
__global__ __launch_bounds__(256) void agg64_kernel(
    const int* __restrict__ rowptr, const int* __restrict__ deg,
    const int2* __restrict__ csr, const ushort* __restrict__ H,
    const float* __restrict__ b, ushort* __restrict__ out, int nR) {
  int lane = threadIdx.x & 63;
  int r = blockIdx.x * 4 + (threadIdx.x >> 6);
  if (r >= nR) return;
  int beg = rowptr[r];
  int d = deg[r];
  int g = lane >> 3;
  int sub = lane & 7;
  float acc[8];
#pragma unroll
  for (int k = 0; k < 8; k++) acc[k] = 0.f;

  for (int j0 = 0; j0 < d; j0 += 8) {
    int jj = j0 + g;
    int2 cw = (jj < d) ? csr[beg + jj] : make_int2(0, 0);  // w=0 pad
    float w = __int_as_float(cw.y);
    int s = cw.x & SRCMASK;
    us8_t hv = *(const us8_t*)&H[(long)s * 64 + sub * 8];
#pragma unroll
    for (int k = 0; k < 8; k++) acc[k] += w * b2f(hv[k]);
  }
#pragma unroll
  for (int off = 8; off < 64; off <<= 1)
#pragma unroll
    for (int k = 0; k < 8; k++) acc[k] += __shfl_xor(acc[k], off, 64);

  if (g == 0) {
    us8_t o;
#pragma unroll
    for (int k = 0; k < 8; k++) {
      float v = acc[k] + b[sub * 8 + k];
      if (RELU) v = fmaxf(v, 0.f);
      o[k] = f2b(v);
    }
    *(us8_t*)&out[(long)r * 64 + sub * 8] = o;
  }
}

// ---------------------------------------------------------------------------
// Layer-3 fused: chunked aggregation (D=40) + bias + log_softmax, fp32 out.
// ---------------------------------------------------------------------------
__global__ __launch_bounds__(256) void agg_lsm_kernel(
    const int* __restrict__ rowptr, const int* __restrict__ deg,
    const int2* __restrict__ csr, const ushort* __restrict__ H,
    const float* __restrict__ b, float* __restrict__ out, int nR) {
  int lane = threadIdx.x & 63;
  int r = blockIdx.x * 4 + (threadIdx.x >> 6);
  if (r >= nR) return;
  int beg = rowptr[r];
  int d = deg[r];
  int g = lane >> 3;
  int sub = lane & 7;
  float acc[8];
#pragma unroll
  for (int k = 0; k < 8; k++) acc[k] = 0.f;

  for (int j0 = 0; j0 < d; j0 += 8) {
    int jj = j0 + g;
    int2 cw = (jj < d) ? csr[beg + jj] : make_int2(0, 0);
    float w = __int_as_float(cw.y);
    int s = cw.x & SRCMASK;
    if (sub < 5) {
      us8_t hv = *(const us8_t*)&H[(long)s * 40 + sub * 8];
#pragma unroll
      for (int k = 0; k < 8; k++) acc[k] += w * b2f(hv[k]);
    }
  }
#pragma unroll
  for (int off = 8; off < 64; off <<= 1)
#pragma unroll
    for (int k = 0; k < 8; k++) acc[k] += __shfl_xor(acc[k], off, 64);

  float v[8];
  float m = -INFINITY, s = 0.f;
  if (sub < 5) {
#pragma unroll
    for (int k = 0; k < 8; k++) {
      v[k] = acc[k] + b[sub * 8 + k];
      m = fmaxf(m, v[k]);
    }
  }
#pragma unroll
  for (int off = 1; off < 8; off <<= 1) m = fmaxf(m, __shfl_xor(m, off, 64));
  if (sub < 5) {
#pragma unroll
    for (int k = 0; k < 8; k++) s += __expf(v[k] - m);
  }
#pragma unroll
  for (int off = 1; off < 8; off <<= 1) s += __shfl_xor(s, off, 64);

  if (g == 0 && sub < 5) {
    float lg = m + __logf(s);
    float4 o0 = make_float4(v[0] - lg, v[1] - lg, v[2] - lg, v[3] - lg);
    float4 o1 = make_float4(v[4] - lg, v[5] - lg, v[6] - lg, v[7] - lg);
    *(float4*)&out[(long)r * 40 + sub * 8] = o0;
    *(float4*)&out[(long)r * 40 + sub * 8 + 4] = o1;
  }
}

extern "C" void kernel_launch(void* const* d_in, const int* in_sizes, int n_in,
                              void* d_out, int out_size, void* d_ws,
                              size_t ws_size, hipStream_t stream) {
  const int* edge_index = (const int*)d_in[0];
  const float* features = (const float*)d_in[1];
  const float* ew = (const float*)d_in[2];
  const float* W1 = (const float*)d_in[3];
  const float* b1 = (const float*)d_in[4];
  const float* W2 = (const float*)d_in[5];
  const float* b2 = (const float*)d_in[6];
  const float* W3 = (const float*)d_in[7];
  const float* b3 = (const float*)d_in[8];
  float* out = (float*)d_out;
  const int* src = edge_index;
  const int* dst = edge_index + NE;

  // workspace layout
  char* p = (char*)d_ws;
  int2* csr = (int2*)p;              p += (size_t)NE * 8;       // 12.8 MB
  int2* esw = (int2*)p;              p += (size_t)NE * 8;       // 12.8 MB
  int* deg = (int*)p;                p += (size_t)NN * 4;
  int* rowptr = (int*)p;             p += (size_t)NN * 4;
  int* bkcnt = (int*)p;              p += 512 * 4;
  int* bkoff = (int*)p;              p += 512 * 4;
  int* bcur = (int*)p;               p += 512 * 4;
  ushort* wswz = (ushort*)p;         p += (size_t)NSLOT * 512 * 2;  // 78 KB
  ushort* hb = (ushort*)p;           p += (size_t)NN * 64 * 2;  // layer buffers
  ushort* xb = (ushort*)p;           p += (size_t)NN * 64 * 2;

  dim3 blk(256);
  const int gemm_grid = (NN + 63) / 64;
  const int row_grid = (NN + 3) / 4;

  // ---- one-time W fragment swizzle (tiny) ----
  wconv_kernel<<<(NSLOT * 64 + 255) / 256, blk, 0, stream>>>(W1, W2, W3, wswz);

  // ---- CSR build v3 (by dst): no global per-edge atomics, coalesced scatter
  hipMemsetAsync(bkcnt, 0, NBUK * sizeof(int), stream);
  histB_kernel<<<(NE + HCHUNK - 1) / HCHUNK, blk, 0, stream>>>(dst, bkcnt);
  scan_bkoff_kernel<<<1, 64, 0, stream>>>(bkcnt, bkoff, bcur);
  bucket_scatter_kernel<<<(NE + CHUNK - 1) / CHUNK, blk, 0, stream>>>(
      src, dst, ew, bcur, esw, NE);
  finalize_kernel<<<NBUK, blk, 0, stream>>>(bkoff, esw, rowptr, deg, csr);

  // ---- layer 1 ----
  gemm_direct<8, 4, 64, true><<<gemm_grid, blk, 0, stream>>>(features, wswz,
                                                             hb, NN);
  agg64_kernel<true><<<row_grid, blk, 0, stream>>>(rowptr, deg, csr, hb, b1,
                                                   xb, NN);
  // ---- layer 2 ----
  gemm_direct<1, 4, 64, false><<<gemm_grid, blk, 0, stream>>>(
      xb, wswz + (size_t)64 * 512, hb, NN);
  agg64_kernel<true><<<row_grid, blk, 0, stream>>>(rowptr, deg, csr, hb, b2,
                                                   xb, NN);
  // ---- layer 3 ----
  gemm_direct<1, 3, 40, false><<<gemm_grid, blk, 0, stream>>>(
      xb, wswz + (size_t)72 * 512, hb, NN);
  agg_lsm_kernel<<<row_grid, blk, 0, stream>>>(rowptr, deg, csr, hb, b3, out,
                                               NN);
}